// Round 17
// baseline (783.071 us; speedup 1.0000x reference)
//
#include <hip/hip_runtime.h>
#include <stdint.h>

// ---- Problem constants -------------------------------------------------
#define DIM   1536
#define NQ    6272      // 8 * 28 * 28 queries
#define NQP   6400      // padded to 25 * 256
#define NB    50000     // bank rows
#define NBP2  50176     // padded to 196 * 256
#define MT2   25
#define NT2   196
#define GRID2 (MT2 * NT2)
#define NKT   24        // 1536 / 64 K-tiles
#define NIT   12        // NKT / 2 iterations
#define NPIX  (8 * 224 * 224)

typedef float f32x4 __attribute__((ext_vector_type(4)));
typedef int   i32x4 __attribute__((ext_vector_type(4)));
typedef __attribute__((address_space(3))) signed char lds_i8;

__device__ inline void gll16(const signed char* g, signed char* l) {
  __builtin_amdgcn_global_load_lds(
      (const __attribute__((address_space(1))) uint32_t*)g,
      (__attribute__((address_space(3))) uint32_t*)l, 16, 0, 0);
}

// ---- init: minbits = +inf, image scores = 0 ---------------------------
__global__ void init_kernel(uint32_t* __restrict__ minbits, float* __restrict__ out_scores) {
  int i = blockIdx.x * 256 + threadIdx.x;
  if (i < NQP) minbits[i] = 0x7F800000u;   // +inf
  if (i < 8)   out_scores[i] = 0.0f;
}

// ---- fp32 -> int8 row quantization + fp32 row norms + scales ----------
// one wave per row; scale = maxabs/127; norm from ORIGINAL fp32 values.
__global__ void quant_rows(const float* __restrict__ src, signed char* __restrict__ dst,
                           float* __restrict__ norms, float* __restrict__ scales,
                           int nsrc, int ndst) {
  int row  = blockIdx.x * 4 + (threadIdx.x >> 6);
  int lane = threadIdx.x & 63;
  if (row >= ndst) return;
  uint32_t* drow = (uint32_t*)(dst + (size_t)row * DIM);
  if (row < nsrc) {
    const float4* s = (const float4*)(src + (size_t)row * DIM);
    float4 v[6]; float ns = 0.f, mx = 0.f;
#pragma unroll
    for (int i = 0; i < 6; ++i) {
      v[i] = s[lane + 64 * i];
      ns += v[i].x * v[i].x + v[i].y * v[i].y + v[i].z * v[i].z + v[i].w * v[i].w;
      mx = fmaxf(mx, fmaxf(fmaxf(fabsf(v[i].x), fabsf(v[i].y)),
                           fmaxf(fabsf(v[i].z), fabsf(v[i].w))));
    }
#pragma unroll
    for (int off = 32; off >= 1; off >>= 1) {
      ns += __shfl_xor(ns, off);
      mx = fmaxf(mx, __shfl_xor(mx, off));
    }
    float inv = (mx > 0.f) ? 127.0f / mx : 0.f;
#pragma unroll
    for (int i = 0; i < 6; ++i) {
      int a = max(-127, min(127, __float2int_rn(v[i].x * inv)));
      int b = max(-127, min(127, __float2int_rn(v[i].y * inv)));
      int c = max(-127, min(127, __float2int_rn(v[i].z * inv)));
      int d = max(-127, min(127, __float2int_rn(v[i].w * inv)));
      drow[lane + 64 * i] = (uint32_t)(a & 255) | ((uint32_t)(b & 255) << 8) |
                            ((uint32_t)(c & 255) << 16) | ((uint32_t)(d & 255) << 24);
    }
    if (lane == 0) { norms[row] = ns; scales[row] = mx * (1.0f / 127.0f); }
  } else {
#pragma unroll
    for (int i = 0; i < 6; ++i) drow[lane + 64 * i] = 0u;
    if (lane == 0) { norms[row] = 1e30f; scales[row] = 0.f; }   // pad never wins
  }
}

// ---- fused 256x256 int8 GEMM + column-min -----------------------------
// BM=BN=256, BK=64, 512 thr = 8 waves (2M x 4N), per-wave 128x64 out.
// mfma_i32_16x16x64_i8; chunk-XOR swizzled 64B-row LDS (0 conflicts).
// 4 PHASES PER 2-TILE ITER (16 MFMA/phase): halves barrier count vs R16;
// per-phase matrix work 652 cyc/SIMD amortizes the ~300-450 cyc fixed
// phase overhead (R16 measured: 8 MFMA/phase -> 37% MfmaUtil, overhead-
// dominated). Counted LGKM keeps only same-phase reads in flight; VM
// gates counted (VM2/VM0-1-phase), never full-queue drains in main loop.
// Stage invariant (R15/16): a stage of region X is issued only after a
// barrier that every wave reached with its X-reads drained.
#define BAR   do { asm volatile("s_barrier" ::: "memory"); \
                   __builtin_amdgcn_sched_barrier(0); } while(0)
#define LGKM(n) do { asm volatile("s_waitcnt lgkmcnt(" #n ")" ::: "memory"); \
                     __builtin_amdgcn_sched_barrier(0); } while(0)
#define VM0   asm volatile("s_waitcnt vmcnt(0)" ::: "memory")
#define VM2   asm volatile("s_waitcnt vmcnt(2)" ::: "memory")
#define PHI   __builtin_amdgcn_s_setprio(1)
#define PLO   __builtin_amdgcn_s_setprio(0)

#define DSR(dst, base, imm) \
  asm volatile("ds_read_b128 %0, %1 offset:%2" : "=v"(dst) : "v"(base), "i"(imm))

// four A m-fragments (frag..frag+3) of buf
#define RD_A4(dst, bufI, frag) do { \
  DSR(dst[0], aOff, (bufI) * 16384 + ((frag) + 0) * 1024); \
  DSR(dst[1], aOff, (bufI) * 16384 + ((frag) + 1) * 1024); \
  DSR(dst[2], aOff, (bufI) * 16384 + ((frag) + 2) * 1024); \
  DSR(dst[3], aOff, (bufI) * 16384 + ((frag) + 3) * 1024); \
} while(0)

// four B n-fragments 0..3 of buf
#define RD_B4(dst, bufI) do { \
  DSR(dst[0], bOff, (bufI) * 16384 + 0);    \
  DSR(dst[1], bOff, (bufI) * 16384 + 1024); \
  DSR(dst[2], bOff, (bufI) * 16384 + 2048); \
  DSR(dst[3], bOff, (bufI) * 16384 + 3072); \
} while(0)

// 16 MFMA: m-quad (mb..mb+3) x 4 n, K=64
#define MFMA16(mb, a4, b4) do { \
  _Pragma("unroll") for (int m_ = 0; m_ < 4; ++m_) \
  _Pragma("unroll") for (int n_ = 0; n_ < 4; ++n_) \
    acc[(mb) + m_][n_] = __builtin_amdgcn_mfma_i32_16x16x64_i8( \
      __builtin_bit_cast(i32x4, a4[m_]), __builtin_bit_cast(i32x4, b4[n_]), \
      acc[(mb) + m_][n_], 0, 0, 0); \
} while(0)

// stage one 256x64 i8 tile (16 KB) = 2 gll16/thread; dest linear,
// source: row = tid>>2 (coalesced 64B segments), chunk permuted by
// (tid&3) ^ ((tid>>3)&3) = c ^ ((row>>1)&3). Row+128 has same xor term.
#define STAGE_A(bufI, ktc) do { \
  const signed char* _g = gA + (size_t)srow * DIM + (ktc) + scol; \
  gll16(_g,                      &sA[bufI][sdst]); \
  gll16(_g + (size_t)128 * DIM,  &sA[bufI][8192 + sdst]); \
} while(0)

#define STAGE_B(bufI, ktc) do { \
  const signed char* _g = gB + (size_t)srow * DIM + (ktc) + scol; \
  gll16(_g,                      &sB[bufI][sdst]); \
  gll16(_g + (size_t)128 * DIM,  &sB[bufI][8192 + sdst]); \
} while(0)

// iter i: tiles t0=2i (buf0: ph1-2) + t1=2i+1 (buf1: ph3-4); T0 = i*128.
// Reads: ph1 aQ(buf0,f4-7)+bO(buf1) [8]; ph2 aP(buf1,f0-3)+aQ(buf1,f4-7)
// [8]; ph3 bE(buf0',f0-3) [4]; ph4 aP(buf0',f0-3) [4].  All gaps >=1 ph.
// Stages: ph1 B0'(t+2); ph3 A0'(t+2)+B1'(t+3); ph4 A1'(t+3).
// WAR (stage after barrier w/ readers drained): B0': bE reads prev-ph3,
// drained prev-ph4 LGKM+BAR. A0': aQ(buf0) ph1, drained ph2 LGKM(8)+BAR.
// B1': bO ph1, drained ph2+BAR. A1': aP/aQ(buf1) ph2, drained ph3 LGKM(4)
// +BAR.  Gates: ph1 VM2 retires A1'(prev) for ph2 reads; ph2 VM0 retires
// B0' for ph3 reads; ph3 VM2 (stage order A0' then B1') retires A0' for
// ph4 reads; ph4 VM2 retires B1' for next-ph1 reads.
#define ITER(T0, SN, TAIL) do { \
  /* ph1 */ RD_A4(aQ, 0, 4); RD_B4(bO, 1); \
    LGKM(8); \
    if (SN) { STAGE_B(0, (T0) + 128); VM2; } else { VM0; } \
    BAR; PHI; MFMA16(0, aP, bE); PLO; \
  /* ph2 */ RD_A4(aP, 1, 0); RD_A4(aQ, 1, 4); \
    LGKM(8); if (SN) { VM0; } \
    BAR; PHI; MFMA16(4, aQ0, bE); PLO; \
  /* ph3 */ if (!TAIL) { RD_B4(bE, 0); } \
    LGKM(4); \
    if (SN) { STAGE_A(0, (T0) + 128); STAGE_B(1, (T0) + 192); VM2; } \
    BAR; PHI; MFMA16(0, aP, bO); PLO; \
  /* ph4 */ if (!TAIL) { RD_A4(aP, 0, 0); LGKM(8); } else { LGKM(0); } \
    if (SN) { STAGE_A(1, (T0) + 192); VM2; } \
    BAR; PHI; MFMA16(4, aQ, bO); PLO; \
} while(0)

__global__ __launch_bounds__(512, 2)
void gemm_min8(const signed char* __restrict__ fA, const signed char* __restrict__ bB,
               const float* __restrict__ bn, const float* __restrict__ bscale,
               const float* __restrict__ qscale, uint32_t* __restrict__ minbits) {
  __shared__ __align__(16) signed char sA[2][16384];   // [buf][256 rows][64] = 32 KiB
  __shared__ __align__(16) signed char sB[2][16384];   // 32 KiB

  const int nwg = GRID2;
  int bid = blockIdx.x;
  const int qch = nwg >> 3, rch = nwg & 7;
  int xcd = bid & 7, loc = bid >> 3;
  int swz = (xcd < rch ? xcd * (qch + 1) : rch * (qch + 1) + (xcd - rch) * qch) + loc;
  int mt = swz % MT2;            // M-fast: consecutive blocks share the B (bank) panel
  int nt = swz / MT2;

  int tid = threadIdx.x;
  int lane = tid & 63, wave = tid >> 6;
  int wm = wave >> 2, wn = wave & 3, bq = wn & 1, bh = wn >> 1;
  int lr = lane & 15, k16 = lane >> 4;

  const signed char* gA = fA + (size_t)(mt * 256) * DIM;
  const signed char* gB = bB + (size_t)(nt * 256) * DIM;

  // staging: row = tid>>2 (coalesced), chunk xor-permuted within 64B
  int srow = tid >> 2;                               // 0..127
  int scol = ((tid & 3) ^ ((tid >> 3) & 3)) * 16;    // permuted 16B chunk
  int sdst = tid * 16;                               // linear dest byte offset

  // read bases with matching chunk xor: data (row=lr, k16) lives at
  // row*64 + (k16 ^ ((row>>1)&3))*16; fragment offsets are immediates.
  int cxA = (k16 ^ ((lr >> 1) & 3)) * 16;
  uint32_t aOff = (uint32_t)(uintptr_t)(lds_i8*)&sA[0][(wm * 128 + lr) * 64 + cxA];
  uint32_t bOff = (uint32_t)(uintptr_t)(lds_i8*)&sB[0][(bh * 128 + bq * 64 + lr) * 64 + cxA];

  i32x4 acc[8][4] = {};
  f32x4 aP[4], aQ[4], bE[4], bO[4];
  // aQ0 alias for ph2 (consumes aQ read in ph1 -- same storage; reads in
  // ph2 overwrite aP/aQ only AFTER their consumers: aP consumed ph3,
  // aQ(new) consumed ph4; aQ(old) consumed ph2 BEFORE ph2's reads land
  // (reads drain at ph3's LGKM). Register WAR on aQ: ph2 issues ds_reads
  // into aQ while MFMA consumes old aQ post-BAR -- HAZARD! Resolve by
  // consuming old aQ from a separate alias read in ph1 is impossible;
  // instead ph2's MFMA uses aQ0 = snapshot? -- NO: the asm ds_read dest
  // registers are written at issue-schedule; the compiler allocates new
  // registers for the new reads only if names differ. Use distinct arrays:
  f32x4 aQ0[4];  // tile-t0 aQ (read ph1), consumed ph2

#define RD_A4Q0() do { \
  DSR(aQ0[0], aOff, 0 * 16384 + 4 * 1024); DSR(aQ0[1], aOff, 0 * 16384 + 5 * 1024); \
  DSR(aQ0[2], aOff, 0 * 16384 + 6 * 1024); DSR(aQ0[3], aOff, 0 * 16384 + 7 * 1024); \
} while(0)

  // prologue: stage tiles 0 (A,B -> buf0) and 1 (B,A -> buf1); VM2 keeps
  // A(1)'s 2 gll16 (= steady-state "prev A1' in flight at ph1 gate");
  // publish; pre-read ph1's consumables: aP(buf0,f0-3) + bE(buf0).
  STAGE_A(0, 0); STAGE_B(0, 0);
  STAGE_B(1, 64); STAGE_A(1, 64);
  VM2; BAR;
  RD_A4(aP, 0, 0); RD_B4(bE, 0);

#pragma unroll 1
  for (int i = 0; i < NIT - 1; ++i) {
    // steady iteration with aQ0 substitution in ph1/ph2
    int T0 = i * 128;
    /* ph1 */ RD_A4Q0(); RD_B4(bO, 1);
      LGKM(8);
      STAGE_B(0, T0 + 128); VM2;
      BAR; PHI; MFMA16(0, aP, bE); PLO;
    /* ph2 */ RD_A4(aP, 1, 0); RD_A4(aQ, 1, 4);
      LGKM(8); VM0;
      BAR; PHI; MFMA16(4, aQ0, bE); PLO;
    /* ph3 */ RD_B4(bE, 0);
      LGKM(4);
      STAGE_A(0, T0 + 128); STAGE_B(1, T0 + 192); VM2;
      BAR; PHI; MFMA16(0, aP, bO); PLO;
    /* ph4 */ RD_A4(aP, 0, 0); LGKM(8);
      STAGE_A(1, T0 + 192); VM2;
      BAR; PHI; MFMA16(4, aQ, bO); PLO;
  }
  {
    // tail: tiles 22 (buf0), 23 (buf1); no stages, no next-iter reads
    /* ph1 */ RD_A4Q0(); RD_B4(bO, 1);
      LGKM(8); VM0;
      BAR; PHI; MFMA16(0, aP, bE); PLO;
    /* ph2 */ RD_A4(aP, 1, 0); RD_A4(aQ, 1, 4);
      LGKM(8);
      BAR; PHI; MFMA16(4, aQ0, bE); PLO;
    /* ph3 */ LGKM(4);
      BAR; PHI; MFMA16(0, aP, bO); PLO;
    /* ph4 */ LGKM(0);
      BAR; PHI; MFMA16(4, aQ, bO); PLO;
  }

  // epilogue: per-row min over this tile's 256 cols of (bn - 2*sq*sb*idot)
  float bnv[4], bsv[4];
#pragma unroll
  for (int n_ = 0; n_ < 4; ++n_) {
    int col = nt * 256 + wn * 64 + n_ * 16 + lr;
    bnv[n_] = bn[col];
    bsv[n_] = 2.0f * bscale[col];
  }
  int qbase = mt * 256 + wm * 128;
#pragma unroll
  for (int m_ = 0; m_ < 8; ++m_) {
    f32x4 sq = *(const f32x4*)&qscale[qbase + m_ * 16 + (lane >> 4) * 4];
#pragma unroll
    for (int r = 0; r < 4; ++r) {
      float sqr = sq[r];
      float v =          bnv[0] - bsv[0] * sqr * (float)acc[m_][0][r];
      v = fminf(v, bnv[1] - bsv[1] * sqr * (float)acc[m_][1][r]);
      v = fminf(v, bnv[2] - bsv[2] * sqr * (float)acc[m_][2][r]);
      v = fminf(v, bnv[3] - bsv[3] * sqr * (float)acc[m_][3][r]);
      // C/D layout (shape-determined): col = lane&15, row = (lane>>4)*4+r
      v = fminf(v, __shfl_xor(v, 1));
      v = fminf(v, __shfl_xor(v, 2));
      v = fminf(v, __shfl_xor(v, 4));
      v = fminf(v, __shfl_xor(v, 8));
      if (lr == 0) {
        int q = qbase + m_ * 16 + (lane >> 4) * 4 + r;
        atomicMin(&minbits[q], __float_as_uint(v));  // positive floats: uint order == float order
      }
    }
  }
}

// ---- patch scores + per-image max -------------------------------------
__global__ void scores_kernel(const uint32_t* __restrict__ minbits, const float* __restrict__ qn,
                              float* __restrict__ ps, float* __restrict__ img) {
  int q = blockIdx.x * 256 + threadIdx.x;
  if (q >= NQ) return;
  float s = __uint_as_float(minbits[q]) + qn[q];
  ps[q] = s;
  atomicMax((uint32_t*)&img[q / 784], __float_as_uint(s));  // scores > 0
}

// ---- bilinear 28x28 -> 224x224 (half-pixel centers, edge clamp) -------
__global__ void resize_kernel(const float* __restrict__ ps, float* __restrict__ masks) {
  int idx = blockIdx.x * 256 + threadIdx.x;
  if (idx >= NPIX) return;
  int b   = idx / (224 * 224);
  int rem = idx - b * (224 * 224);
  int oy  = rem / 224;
  int ox  = rem - oy * 224;
  float sy = (oy + 0.5f) * 0.125f - 0.5f;
  float sx = (ox + 0.5f) * 0.125f - 0.5f;
  float fy0 = floorf(sy), fx0 = floorf(sx);
  int y0 = (int)fy0, x0 = (int)fx0;
  float fy = sy - fy0, fx = sx - fx0;
  int y0c = min(max(y0, 0), 27),     y1c = min(max(y0 + 1, 0), 27);
  int x0c = min(max(x0, 0), 27),     x1c = min(max(x0 + 1, 0), 27);
  const float* p = ps + b * 784;
  float top = p[y0c * 28 + x0c] * (1.f - fx) + p[y0c * 28 + x1c] * fx;
  float bot = p[y1c * 28 + x0c] * (1.f - fx) + p[y1c * 28 + x1c] * fx;
  masks[idx] = top * (1.f - fy) + bot * fy;
}

// ---- host launch -------------------------------------------------------
extern "C" void kernel_launch(void* const* d_in, const int* in_sizes, int n_in,
                              void* d_out, int out_size, void* d_ws, size_t ws_size,
                              hipStream_t stream) {
  const float* features = (const float*)d_in[0];   // [6272, 1536]
  const float* bank     = (const float*)d_in[1];   // [50000, 1536]

  char* ws = (char*)d_ws;
  size_t off = 0;
  signed char* bankQ = (signed char*)(ws + off); off += (size_t)NBP2 * DIM;   // 77.1 MB
  signed char* featQ = (signed char*)(ws + off); off += (size_t)NQP * DIM;    //  9.8 MB
  float*    bn      = (float*)(ws + off);    off += (size_t)NBP2 * 4;
  float*    qn      = (float*)(ws + off);    off += (size_t)NQP * 4;
  float*    bscale  = (float*)(ws + off);    off += (size_t)NBP2 * 4;
  float*    qscale  = (float*)(ws + off);    off += (size_t)NQP * 4;
  uint32_t* minbits = (uint32_t*)(ws + off); off += (size_t)NQP * 4;
  float*    ps      = (float*)(ws + off);    off += (size_t)NQ * 4;

  float* out_scores = (float*)d_out;       // [8]
  float* masks      = out_scores + 8;      // [8,224,224]

  hipLaunchKernelGGL(init_kernel, dim3(25), dim3(256), 0, stream, minbits, out_scores);
  hipLaunchKernelGGL(quant_rows, dim3(NBP2 / 4), dim3(256), 0, stream, bank, bankQ, bn, bscale, NB, NBP2);
  hipLaunchKernelGGL(quant_rows, dim3(NQP / 4), dim3(256), 0, stream, features, featQ, qn, qscale, NQ, NQP);
  hipLaunchKernelGGL(gemm_min8, dim3(GRID2), dim3(512), 0, stream, featQ, bankQ, bn, bscale, qscale, minbits);
  hipLaunchKernelGGL(scores_kernel, dim3(25), dim3(256), 0, stream, minbits, qn, ps, out_scores);
  hipLaunchKernelGGL(resize_kernel, dim3((NPIX + 255) / 256), dim3(256), 0, stream, ps, masks);
}

// Round 18
// 703.792 us; speedup vs baseline: 1.1126x; 1.1126x over previous
//
#include <hip/hip_runtime.h>
#include <stdint.h>

// ---- Problem constants -------------------------------------------------
#define DIM   1536
#define NQ    6272      // 8 * 28 * 28 queries
#define NQP   6400      // padded to 25 * 256
#define NB    50000     // bank rows
#define NBP2  50176     // padded to 196 * 256
#define MT2   25
#define NT2   196
#define GRID2 (MT2 * NT2)
#define NKT   24        // 1536 / 64 K-tiles
#define NIT   12        // NKT / 2 iterations
#define NPIX  (8 * 224 * 224)

typedef float f32x4 __attribute__((ext_vector_type(4)));
typedef int   i32x4 __attribute__((ext_vector_type(4)));
typedef __attribute__((address_space(3))) signed char lds_i8;

__device__ inline void gll16(const signed char* g, signed char* l) {
  __builtin_amdgcn_global_load_lds(
      (const __attribute__((address_space(1))) uint32_t*)g,
      (__attribute__((address_space(3))) uint32_t*)l, 16, 0, 0);
}

// ---- init: minbits = +inf, image scores = 0 ---------------------------
__global__ void init_kernel(uint32_t* __restrict__ minbits, float* __restrict__ out_scores) {
  int i = blockIdx.x * 256 + threadIdx.x;
  if (i < NQP) minbits[i] = 0x7F800000u;   // +inf
  if (i < 8)   out_scores[i] = 0.0f;
}

// ---- fp32 -> int8 row quantization + fp32 row norms + scales ----------
// one wave per row; scale = maxabs/127; norm from ORIGINAL fp32 values.
__global__ void quant_rows(const float* __restrict__ src, signed char* __restrict__ dst,
                           float* __restrict__ norms, float* __restrict__ scales,
                           int nsrc, int ndst) {
  int row  = blockIdx.x * 4 + (threadIdx.x >> 6);
  int lane = threadIdx.x & 63;
  if (row >= ndst) return;
  uint32_t* drow = (uint32_t*)(dst + (size_t)row * DIM);
  if (row < nsrc) {
    const float4* s = (const float4*)(src + (size_t)row * DIM);
    float4 v[6]; float ns = 0.f, mx = 0.f;
#pragma unroll
    for (int i = 0; i < 6; ++i) {
      v[i] = s[lane + 64 * i];
      ns += v[i].x * v[i].x + v[i].y * v[i].y + v[i].z * v[i].z + v[i].w * v[i].w;
      mx = fmaxf(mx, fmaxf(fmaxf(fabsf(v[i].x), fabsf(v[i].y)),
                           fmaxf(fabsf(v[i].z), fabsf(v[i].w))));
    }
#pragma unroll
    for (int off = 32; off >= 1; off >>= 1) {
      ns += __shfl_xor(ns, off);
      mx = fmaxf(mx, __shfl_xor(mx, off));
    }
    float inv = (mx > 0.f) ? 127.0f / mx : 0.f;
#pragma unroll
    for (int i = 0; i < 6; ++i) {
      int a = max(-127, min(127, __float2int_rn(v[i].x * inv)));
      int b = max(-127, min(127, __float2int_rn(v[i].y * inv)));
      int c = max(-127, min(127, __float2int_rn(v[i].z * inv)));
      int d = max(-127, min(127, __float2int_rn(v[i].w * inv)));
      drow[lane + 64 * i] = (uint32_t)(a & 255) | ((uint32_t)(b & 255) << 8) |
                            ((uint32_t)(c & 255) << 16) | ((uint32_t)(d & 255) << 24);
    }
    if (lane == 0) { norms[row] = ns; scales[row] = mx * (1.0f / 127.0f); }
  } else {
#pragma unroll
    for (int i = 0; i < 6; ++i) drow[lane + 64 * i] = 0u;
    if (lane == 0) { norms[row] = 1e30f; scales[row] = 0.f; }   // pad never wins
  }
}

// ---- fused 256x256 int8 GEMM + column-min -----------------------------
// BM=BN=256, BK=64, 512 thr = 8 waves (2M x 4N), per-wave 128x64 out.
// mfma_i32_16x16x64_i8; chunk-XOR swizzled 64B-row LDS (0 conflicts).
// 6 PHASES PER 2-TILE ITER: R15's 8-phase with ph3+4 / ph7+8 merged (the
// gate-free phases). VM gates stay COUNTED (VM2, 2-phase stage flight) --
// fixes R17's every-iter VM0 stall. New: LGKM(0) at P2/P6 moves the
// aQ-reader drain one barrier earlier so the merged phases' A-stage obeys
// the invariant: a stage of region X issues only after a barrier that all
// waves reached with their X-reads drained.
#define BAR   do { asm volatile("s_barrier" ::: "memory"); \
                   __builtin_amdgcn_sched_barrier(0); } while(0)
#define LGKM(n) do { asm volatile("s_waitcnt lgkmcnt(" #n ")" ::: "memory"); \
                     __builtin_amdgcn_sched_barrier(0); } while(0)
#define VM0   asm volatile("s_waitcnt vmcnt(0)" ::: "memory")
#define VM2   asm volatile("s_waitcnt vmcnt(2)" ::: "memory")
#define PHI   __builtin_amdgcn_s_setprio(1)
#define PLO   __builtin_amdgcn_s_setprio(0)

#define DSR(dst, base, imm) \
  asm volatile("ds_read_b128 %0, %1 offset:%2" : "=v"(dst) : "v"(base), "i"(imm))

// A quad: m-fragments quad*4..quad*4+3 (rows m*16+lr), 1024B apart
#define READ_AQ(dst, bufI, quad) do { \
  DSR(dst[0], aOff, (bufI) * 16384 + (quad) * 4096 + 0);    \
  DSR(dst[1], aOff, (bufI) * 16384 + (quad) * 4096 + 1024); \
  DSR(dst[2], aOff, (bufI) * 16384 + (quad) * 4096 + 2048); \
  DSR(dst[3], aOff, (bufI) * 16384 + (quad) * 4096 + 3072); \
} while(0)

// B quad: n-fragments 0..3 (rows bh*128+bq*64+n*16+lr)
#define READ_B4(dst, bufI) do { \
  DSR(dst[0], bOff, (bufI) * 16384 + 0);    \
  DSR(dst[1], bOff, (bufI) * 16384 + 1024); \
  DSR(dst[2], bOff, (bufI) * 16384 + 2048); \
  DSR(dst[3], bOff, (bufI) * 16384 + 3072); \
} while(0)

// 8 MFMA: m-pair (mb, mb+1) x 4 n, K=64
#define MFMA8(mb, x0, x1, b4) do { \
  _Pragma("unroll") for (int n_ = 0; n_ < 4; ++n_) { \
    acc[(mb)][n_]     = __builtin_amdgcn_mfma_i32_16x16x64_i8( \
      __builtin_bit_cast(i32x4, (x0)), __builtin_bit_cast(i32x4, b4[n_]), acc[(mb)][n_], 0, 0, 0); \
    acc[(mb) + 1][n_] = __builtin_amdgcn_mfma_i32_16x16x64_i8( \
      __builtin_bit_cast(i32x4, (x1)), __builtin_bit_cast(i32x4, b4[n_]), acc[(mb) + 1][n_], 0, 0, 0); \
  } \
} while(0)

// 16 MFMA: m-quad (mb..mb+3) x 4 n, K=64
#define MFMA16(mb, a4, b4) do { \
  _Pragma("unroll") for (int m_ = 0; m_ < 4; ++m_) \
  _Pragma("unroll") for (int n_ = 0; n_ < 4; ++n_) \
    acc[(mb) + m_][n_] = __builtin_amdgcn_mfma_i32_16x16x64_i8( \
      __builtin_bit_cast(i32x4, a4[m_]), __builtin_bit_cast(i32x4, b4[n_]), \
      acc[(mb) + m_][n_], 0, 0, 0); \
} while(0)

// stage one 256x64 i8 tile (16 KB) = 2 gll16/thread; dest linear,
// source: row = tid>>2 (coalesced 64B segments), chunk permuted by
// (tid&3) ^ ((tid>>3)&3) = c ^ ((row>>1)&3). Row+128 has same xor term.
#define STAGE_A(bufI, ktc) do { \
  const signed char* _g = gA + (size_t)srow * DIM + (ktc) + scol; \
  gll16(_g,                      &sA[bufI][sdst]); \
  gll16(_g + (size_t)128 * DIM,  &sA[bufI][8192 + sdst]); \
} while(0)

#define STAGE_B(bufI, ktc) do { \
  const signed char* _g = gB + (size_t)srow * DIM + (ktc) + scol; \
  gll16(_g,                      &sB[bufI][sdst]); \
  gll16(_g + (size_t)128 * DIM,  &sB[bufI][8192 + sdst]); \
} while(0)

// iter i: tiles t0=2i (buf0: P1,P2,P34) + t1=2i+1 (buf1: P5,P6,P78).
// Reads: P1 aQ(buf0,q1)[4]; P34 aP(buf1,q0)+bO(buf1)[8]; P5 aQ(buf1,q1)[4];
//        P78 aP(buf0',q0)+bE(buf0')[8].  All consumed >=1 wait later.
// Stages: P2 B0'(t+2); P34 A0'(t+2); P6 B1'(t+3); P78 A1'(t+3).
// WAR: A0' needs aQ(buf0,P1) drained at P2's LGKM(0)+BAR; A1' needs
// aQ(buf1,P5) drained at P6's LGKM(0)+BAR; B0' readers drained prev-P5;
// B1' readers (bO,P34) drained P5's LGKM(4)+BAR. All hold.
// RAW gates: P2 VM2 retires {B1',A1' prev} keeps own B0' -> P34 reads
// buf1 safe; P6 VM2 retires {B0',A0'} keeps own B1' -> P78 reads buf0'
// safe. Steady outstanding entering P1 = 4. Tail: VM0 at P2.
#define ITER6(T0, SN, TAIL) do { \
  /* P1 */ READ_AQ(aQ, 0, 1); \
    LGKM(4); \
    BAR; PHI; MFMA8(0, aP[0], aP[1], bE); PLO; \
  /* P2 */ LGKM(0); \
    if (SN) { STAGE_B(0, (T0) + 128); VM2; } else { VM0; } \
    BAR; PHI; MFMA8(2, aP[2], aP[3], bE); PLO; \
  /* P34 */ READ_AQ(aP, 1, 0); READ_B4(bO, 1); \
    LGKM(8); \
    if (SN) STAGE_A(0, (T0) + 128); \
    BAR; PHI; MFMA16(4, aQ, bE); PLO; \
  /* P5 */ READ_AQ(aQ, 1, 1); \
    LGKM(4); \
    BAR; PHI; MFMA8(0, aP[0], aP[1], bO); PLO; \
  /* P6 */ LGKM(0); \
    if (SN) { STAGE_B(1, (T0) + 192); VM2; } \
    BAR; PHI; MFMA8(2, aP[2], aP[3], bO); PLO; \
  /* P78 */ if (!TAIL) { READ_AQ(aP, 0, 0); READ_B4(bE, 0); LGKM(8); } \
    else { LGKM(0); } \
    if (SN) STAGE_A(1, (T0) + 192); \
    BAR; PHI; MFMA16(4, aQ, bO); PLO; \
} while(0)

__global__ __launch_bounds__(512, 2)
void gemm_min8(const signed char* __restrict__ fA, const signed char* __restrict__ bB,
               const float* __restrict__ bn, const float* __restrict__ bscale,
               const float* __restrict__ qscale, uint32_t* __restrict__ minbits) {
  __shared__ __align__(16) signed char sA[2][16384];   // [buf][256 rows][64] = 32 KiB
  __shared__ __align__(16) signed char sB[2][16384];   // 32 KiB

  const int nwg = GRID2;
  int bid = blockIdx.x;
  const int qch = nwg >> 3, rch = nwg & 7;
  int xcd = bid & 7, loc = bid >> 3;
  int swz = (xcd < rch ? xcd * (qch + 1) : rch * (qch + 1) + (xcd - rch) * qch) + loc;
  int mt = swz % MT2;            // M-fast: consecutive blocks share the B (bank) panel
  int nt = swz / MT2;

  int tid = threadIdx.x;
  int lane = tid & 63, wave = tid >> 6;
  int wm = wave >> 2, wn = wave & 3, bq = wn & 1, bh = wn >> 1;
  int lr = lane & 15, k16 = lane >> 4;

  const signed char* gA = fA + (size_t)(mt * 256) * DIM;
  const signed char* gB = bB + (size_t)(nt * 256) * DIM;

  // staging: row = tid>>2 (coalesced), chunk xor-permuted within 64B
  int srow = tid >> 2;                               // 0..127
  int scol = ((tid & 3) ^ ((tid >> 3) & 3)) * 16;    // permuted 16B chunk
  int sdst = tid * 16;                               // linear dest byte offset

  // read bases with matching chunk xor: data (row=lr, k16) lives at
  // row*64 + (k16 ^ ((row>>1)&3))*16; fragment offsets are immediates.
  int cxA = (k16 ^ ((lr >> 1) & 3)) * 16;
  uint32_t aOff = (uint32_t)(uintptr_t)(lds_i8*)&sA[0][(wm * 128 + lr) * 64 + cxA];
  uint32_t bOff = (uint32_t)(uintptr_t)(lds_i8*)&sB[0][(bh * 128 + bq * 64 + lr) * 64 + cxA];

  i32x4 acc[8][4] = {};
  f32x4 aP[4], aQ[4], bE[4], bO[4];

  // prologue: stage tiles 0 (buf0 A+B) and 1 (buf1 B then A); VM2 retires
  // {A0,B0,B1}, keeps A1 (retired at first P2's VM2, published its BAR --
  // P34 is the first buf1 reader, after that barrier). Publish; pre-read
  // P1's consumables: aP(buf0,f0-3) + bE(buf0); drained by P1's LGKM(4).
  STAGE_A(0, 0); STAGE_B(0, 0);
  STAGE_B(1, 64); STAGE_A(1, 64);
  VM2; BAR;
  READ_AQ(aP, 0, 0); READ_B4(bE, 0);

#pragma unroll 1
  for (int i = 0; i < NIT - 1; ++i) {
    ITER6(i * 128, 1, 0);
  }
  ITER6((NIT - 1) * 128, 0, 1);   // tiles 22,23: no stages, no next-iter reads

  // epilogue: per-row min over this tile's 256 cols of (bn - 2*sq*sb*idot)
  float bnv[4], bsv[4];
#pragma unroll
  for (int n_ = 0; n_ < 4; ++n_) {
    int col = nt * 256 + wn * 64 + n_ * 16 + lr;
    bnv[n_] = bn[col];
    bsv[n_] = 2.0f * bscale[col];
  }
  int qbase = mt * 256 + wm * 128;
#pragma unroll
  for (int m_ = 0; m_ < 8; ++m_) {
    f32x4 sq = *(const f32x4*)&qscale[qbase + m_ * 16 + (lane >> 4) * 4];
#pragma unroll
    for (int r = 0; r < 4; ++r) {
      float sqr = sq[r];
      float v =          bnv[0] - bsv[0] * sqr * (float)acc[m_][0][r];
      v = fminf(v, bnv[1] - bsv[1] * sqr * (float)acc[m_][1][r]);
      v = fminf(v, bnv[2] - bsv[2] * sqr * (float)acc[m_][2][r]);
      v = fminf(v, bnv[3] - bsv[3] * sqr * (float)acc[m_][3][r]);
      // C/D layout (shape-determined): col = lane&15, row = (lane>>4)*4+r
      v = fminf(v, __shfl_xor(v, 1));
      v = fminf(v, __shfl_xor(v, 2));
      v = fminf(v, __shfl_xor(v, 4));
      v = fminf(v, __shfl_xor(v, 8));
      if (lr == 0) {
        int q = qbase + m_ * 16 + (lane >> 4) * 4 + r;
        atomicMin(&minbits[q], __float_as_uint(v));  // positive floats: uint order == float order
      }
    }
  }
}

// ---- patch scores + per-image max -------------------------------------
__global__ void scores_kernel(const uint32_t* __restrict__ minbits, const float* __restrict__ qn,
                              float* __restrict__ ps, float* __restrict__ img) {
  int q = blockIdx.x * 256 + threadIdx.x;
  if (q >= NQ) return;
  float s = __uint_as_float(minbits[q]) + qn[q];
  ps[q] = s;
  atomicMax((uint32_t*)&img[q / 784], __float_as_uint(s));  // scores > 0
}

// ---- bilinear 28x28 -> 224x224 (half-pixel centers, edge clamp) -------
__global__ void resize_kernel(const float* __restrict__ ps, float* __restrict__ masks) {
  int idx = blockIdx.x * 256 + threadIdx.x;
  if (idx >= NPIX) return;
  int b   = idx / (224 * 224);
  int rem = idx - b * (224 * 224);
  int oy  = rem / 224;
  int ox  = rem - oy * 224;
  float sy = (oy + 0.5f) * 0.125f - 0.5f;
  float sx = (ox + 0.5f) * 0.125f - 0.5f;
  float fy0 = floorf(sy), fx0 = floorf(sx);
  int y0 = (int)fy0, x0 = (int)fx0;
  float fy = sy - fy0, fx = sx - fx0;
  int y0c = min(max(y0, 0), 27),     y1c = min(max(y0 + 1, 0), 27);
  int x0c = min(max(x0, 0), 27),     x1c = min(max(x0 + 1, 0), 27);
  const float* p = ps + b * 784;
  float top = p[y0c * 28 + x0c] * (1.f - fx) + p[y0c * 28 + x1c] * fx;
  float bot = p[y1c * 28 + x0c] * (1.f - fx) + p[y1c * 28 + x1c] * fx;
  masks[idx] = top * (1.f - fy) + bot * fy;
}

// ---- host launch -------------------------------------------------------
extern "C" void kernel_launch(void* const* d_in, const int* in_sizes, int n_in,
                              void* d_out, int out_size, void* d_ws, size_t ws_size,
                              hipStream_t stream) {
  const float* features = (const float*)d_in[0];   // [6272, 1536]
  const float* bank     = (const float*)d_in[1];   // [50000, 1536]

  char* ws = (char*)d_ws;
  size_t off = 0;
  signed char* bankQ = (signed char*)(ws + off); off += (size_t)NBP2 * DIM;   // 77.1 MB
  signed char* featQ = (signed char*)(ws + off); off += (size_t)NQP * DIM;    //  9.8 MB
  float*    bn      = (float*)(ws + off);    off += (size_t)NBP2 * 4;
  float*    qn      = (float*)(ws + off);    off += (size_t)NQP * 4;
  float*    bscale  = (float*)(ws + off);    off += (size_t)NBP2 * 4;
  float*    qscale  = (float*)(ws + off);    off += (size_t)NQP * 4;
  uint32_t* minbits = (uint32_t*)(ws + off); off += (size_t)NQP * 4;
  float*    ps      = (float*)(ws + off);    off += (size_t)NQ * 4;

  float* out_scores = (float*)d_out;       // [8]
  float* masks      = out_scores + 8;      // [8,224,224]

  hipLaunchKernelGGL(init_kernel, dim3(25), dim3(256), 0, stream, minbits, out_scores);
  hipLaunchKernelGGL(quant_rows, dim3(NBP2 / 4), dim3(256), 0, stream, bank, bankQ, bn, bscale, NB, NBP2);
  hipLaunchKernelGGL(quant_rows, dim3(NQP / 4), dim3(256), 0, stream, features, featQ, qn, qscale, NQ, NQP);
  hipLaunchKernelGGL(gemm_min8, dim3(GRID2), dim3(512), 0, stream, featQ, bankQ, bn, bscale, qscale, minbits);
  hipLaunchKernelGGL(scores_kernel, dim3(25), dim3(256), 0, stream, minbits, qn, ps, out_scores);
  hipLaunchKernelGGL(resize_kernel, dim3((NPIX + 255) / 256), dim3(256), 0, stream, ps, masks);
}

// Round 19
// 662.256 us; speedup vs baseline: 1.1824x; 1.0627x over previous
//
#include <hip/hip_runtime.h>
#include <stdint.h>

// ---- Problem constants -------------------------------------------------
#define DIM   1536
#define NQ    6272      // 8 * 28 * 28 queries
#define NQP   6400      // padded to 50 * 128
#define NB    50000     // bank rows
#define NBP2  50176     // padded to 196 * 256
#define MT3   50
#define NT3   196
#define GRID3 (MT3 * NT3)   // 9800
#define NPIX  (8 * 224 * 224)

typedef float f32x4 __attribute__((ext_vector_type(4)));
typedef int   i32x4 __attribute__((ext_vector_type(4)));
typedef __attribute__((address_space(3))) signed char lds_i8;

__device__ inline void gll16(const signed char* g, signed char* l) {
  __builtin_amdgcn_global_load_lds(
      (const __attribute__((address_space(1))) uint32_t*)g,
      (__attribute__((address_space(3))) uint32_t*)l, 16, 0, 0);
}

// ---- init: minbits = +inf, image scores = 0 ---------------------------
__global__ void init_kernel(uint32_t* __restrict__ minbits, float* __restrict__ out_scores) {
  int i = blockIdx.x * 256 + threadIdx.x;
  if (i < NQP) minbits[i] = 0x7F800000u;   // +inf
  if (i < 8)   out_scores[i] = 0.0f;
}

// ---- fp32 -> int8 row quantization + fp32 row norms + scales ----------
__global__ void quant_rows(const float* __restrict__ src, signed char* __restrict__ dst,
                           float* __restrict__ norms, float* __restrict__ scales,
                           int nsrc, int ndst) {
  int row  = blockIdx.x * 4 + (threadIdx.x >> 6);
  int lane = threadIdx.x & 63;
  if (row >= ndst) return;
  uint32_t* drow = (uint32_t*)(dst + (size_t)row * DIM);
  if (row < nsrc) {
    const float4* s = (const float4*)(src + (size_t)row * DIM);
    float4 v[6]; float ns = 0.f, mx = 0.f;
#pragma unroll
    for (int i = 0; i < 6; ++i) {
      v[i] = s[lane + 64 * i];
      ns += v[i].x * v[i].x + v[i].y * v[i].y + v[i].z * v[i].z + v[i].w * v[i].w;
      mx = fmaxf(mx, fmaxf(fmaxf(fabsf(v[i].x), fabsf(v[i].y)),
                           fmaxf(fabsf(v[i].z), fabsf(v[i].w))));
    }
#pragma unroll
    for (int off = 32; off >= 1; off >>= 1) {
      ns += __shfl_xor(ns, off);
      mx = fmaxf(mx, __shfl_xor(mx, off));
    }
    float inv = (mx > 0.f) ? 127.0f / mx : 0.f;
#pragma unroll
    for (int i = 0; i < 6; ++i) {
      int a = max(-127, min(127, __float2int_rn(v[i].x * inv)));
      int b = max(-127, min(127, __float2int_rn(v[i].y * inv)));
      int c = max(-127, min(127, __float2int_rn(v[i].z * inv)));
      int d = max(-127, min(127, __float2int_rn(v[i].w * inv)));
      drow[lane + 64 * i] = (uint32_t)(a & 255) | ((uint32_t)(b & 255) << 8) |
                            ((uint32_t)(c & 255) << 16) | ((uint32_t)(d & 255) << 24);
    }
    if (lane == 0) { norms[row] = ns; scales[row] = mx * (1.0f / 127.0f); }
  } else {
#pragma unroll
    for (int i = 0; i < 6; ++i) drow[lane + 64 * i] = 0u;
    if (lane == 0) { norms[row] = 1e30f; scales[row] = 0.f; }   // pad never wins
  }
}

// ---- fused 128x256 int8 GEMM + column-min, 2 blocks/CU ----------------
// BM=128, BN=256, 512 thr = 8 waves (2M x 4N), per-wave 64x64 out.
// acc = 64 regs; single-banked frags (a 16 + b 16) -> ~112 regs total,
// capped at 128 by __launch_bounds__(512,4) => 4 waves/SIMD = 2 blocks/CU
// (fixes the 1-block cap: acc-128 + frags put prior kernels at ~252 regs,
// 2 waves/SIMD -- every barrier was dead time; occupancy stuck at 22%).
// LDS: 3 buffers A(8K)+B(16K) = 72 KiB -> 2 blocks fit (147 KiB).
// Schedule: 2 phases/tile, pre-BAR LGKM(0) (strict publish invariant);
// tile u stages tile u+2 at P_a (3-phase flight), counted VM3 gate at
// P_b retires tile u+1's stages only. Chunk-XOR swizzle (R15): LDS
// (row, slot c) holds chunk c ^ ((row>>1)&3) -> conflict-free + coalesced.
#define BAR   do { asm volatile("s_barrier" ::: "memory"); \
                   __builtin_amdgcn_sched_barrier(0); } while(0)
#define LGKM0 do { asm volatile("s_waitcnt lgkmcnt(0)" ::: "memory"); \
                   __builtin_amdgcn_sched_barrier(0); } while(0)
#define VM0   asm volatile("s_waitcnt vmcnt(0)" ::: "memory")
#define VM3   asm volatile("s_waitcnt vmcnt(3)" ::: "memory")
#define PHI   __builtin_amdgcn_s_setprio(1)
#define PLO   __builtin_amdgcn_s_setprio(0)

#define DSR(dst, base, imm) \
  asm volatile("ds_read_b128 %0, %1 offset:%2" : "=v"(dst) : "v"(base), "i"(imm))

// 8 MFMA: 4 m-frags x 2 n-frags (nb, nb+1), K=64
#define MFMA8N(nb, bb) do { \
  _Pragma("unroll") for (int m_ = 0; m_ < 4; ++m_) \
  _Pragma("unroll") for (int n_ = 0; n_ < 2; ++n_) \
    acc[m_][(nb) + n_] = __builtin_amdgcn_mfma_i32_16x16x64_i8( \
      __builtin_bit_cast(i32x4, a[m_]), __builtin_bit_cast(i32x4, bb[n_]), \
      acc[m_][(nb) + n_], 0, 0, 0); \
} while(0)

// stage tile -> buf: A 128x64 (1 gll16), B 256x64 (2 gll16); dest linear,
// source row = tid>>2 (coalesced 64B segs), chunk (tid&3)^((tid>>3)&3).
#define STAGE_AB(sb, ktc) do { \
  gll16(gA + gOffA + (ktc), &sA[sb][sdst]); \
  const signed char* _g = gB + gOffA + (ktc); \
  gll16(_g,                      &sB[sb][sdst]); \
  gll16(_g + (size_t)128 * DIM,  &sB[sb][8192 + sdst]); \
} while(0)

// P_a: read a[4] + b01[2] of buf; optional stage of tile u+2; drain; BAR;
//      MFMA n0-1.   P_b: read b23[2]; drain; gate; BAR; MFMA n2-3.
#define PH_A(buf, SN, sb, ktc) do { \
  DSR(a[0], aOff, (buf) * 8192 + 0);    DSR(a[1], aOff, (buf) * 8192 + 1024); \
  DSR(a[2], aOff, (buf) * 8192 + 2048); DSR(a[3], aOff, (buf) * 8192 + 3072); \
  DSR(b01[0], bOff, (buf) * 16384 + 0); DSR(b01[1], bOff, (buf) * 16384 + 1024); \
  if (SN) STAGE_AB(sb, ktc); \
  LGKM0; BAR; PHI; MFMA8N(0, b01); PLO; \
} while(0)

#define PH_B(buf, GATE) do { \
  DSR(b23[0], bOff, (buf) * 16384 + 2048); DSR(b23[1], bOff, (buf) * 16384 + 3072); \
  LGKM0; GATE; BAR; PHI; MFMA8N(2, b23); PLO; \
} while(0)

__global__ __launch_bounds__(512, 4)
void gemm_min8(const signed char* __restrict__ fA, const signed char* __restrict__ bB,
               const float* __restrict__ bn, const float* __restrict__ bscale,
               const float* __restrict__ qscale, uint32_t* __restrict__ minbits) {
  __shared__ __align__(16) signed char sA[3][8192];    // 24 KiB
  __shared__ __align__(16) signed char sB[3][16384];   // 48 KiB

  const int nwg = GRID3;
  int bid = blockIdx.x;
  const int qch = nwg >> 3, rch = nwg & 7;
  int xcd = bid & 7, loc = bid >> 3;
  int swz = (xcd < rch ? xcd * (qch + 1) : rch * (qch + 1) + (xcd - rch) * qch) + loc;
  int mt = swz % MT3;            // M-fast: consecutive blocks share the B (bank) panel
  int nt = swz / MT3;

  int tid = threadIdx.x;
  int lane = tid & 63, wave = tid >> 6;
  int wm = wave >> 2, wn = wave & 3;
  int lr = lane & 15, k16 = lane >> 4;

  const signed char* gA = fA + (size_t)(mt * 128) * DIM;
  const signed char* gB = bB + (size_t)(nt * 256) * DIM;

  // staging: row = tid>>2 (A rows 0-127; B also +128), chunk xor-permuted
  size_t gOffA = (size_t)(tid >> 2) * DIM + ((tid & 3) ^ ((tid >> 3) & 3)) * 16;
  int sdst = tid * 16;

  // read bases: data (row, k16) at row*64 + (k16 ^ ((row>>1)&3))*16
  int cxA = (k16 ^ ((lr >> 1) & 3)) * 16;
  uint32_t aOff = (uint32_t)(uintptr_t)(lds_i8*)&sA[0][(wm * 64 + lr) * 64 + cxA];
  uint32_t bOff = (uint32_t)(uintptr_t)(lds_i8*)&sB[0][(wn * 64 + lr) * 64 + cxA];

  i32x4 acc[4][4] = {};
  f32x4 a[4], b01[2], b23[2];

  // prologue: stage tiles 0 (buf0) + 1 (buf1); VM3 retires t0's 3 gll16
  // (keeps t1's 3 in flight, retired at t0's P_b gate); publish.
  STAGE_AB(0, 0);
  STAGE_AB(1, 64);
  VM3; BAR;

  // 7 full iterations: tiles 3j, 3j+1, 3j+2 in bufs 0,1,2; each tile u
  // stages tile u+2 at P_a; VM3 gate at P_b retires tile u+1's stages.
#pragma unroll 1
  for (int j = 0; j < 7; ++j) {
    int kb = j * 192;
    PH_A(0, 1, 2, kb + 128); PH_B(0, VM3);   // tile 3j   : stage 3j+2 -> buf2
    PH_A(1, 1, 0, kb + 192); PH_B(1, VM3);   // tile 3j+1 : stage 3j+3 -> buf0
    PH_A(2, 1, 1, kb + 256); PH_B(2, VM3);   // tile 3j+2 : stage 3j+4 -> buf1
  }
  // tail: tiles 21 (buf0, stages t23->buf2), 22 (buf1), 23 (buf2)
  PH_A(0, 1, 2, 1472); PH_B(0, VM3);
  PH_A(1, 0, 0, 0);    PH_B(1, VM0);
  PH_A(2, 0, 0, 0);    PH_B(2, ;);

  // epilogue: per-row min over this tile's 256 cols of (bn - 2*sq*sb*idot)
  float bnv[4], bsv[4];
#pragma unroll
  for (int n_ = 0; n_ < 4; ++n_) {
    int col = nt * 256 + wn * 64 + n_ * 16 + lr;
    bnv[n_] = bn[col];
    bsv[n_] = 2.0f * bscale[col];
  }
  int qbase = mt * 128 + wm * 64;
#pragma unroll
  for (int m_ = 0; m_ < 4; ++m_) {
    f32x4 sq = *(const f32x4*)&qscale[qbase + m_ * 16 + (lane >> 4) * 4];
#pragma unroll
    for (int r = 0; r < 4; ++r) {
      float sqr = sq[r];
      float v =          bnv[0] - bsv[0] * sqr * (float)acc[m_][0][r];
      v = fminf(v, bnv[1] - bsv[1] * sqr * (float)acc[m_][1][r]);
      v = fminf(v, bnv[2] - bsv[2] * sqr * (float)acc[m_][2][r]);
      v = fminf(v, bnv[3] - bsv[3] * sqr * (float)acc[m_][3][r]);
      // C/D layout (shape-determined): col = lane&15, row = (lane>>4)*4+r
      v = fminf(v, __shfl_xor(v, 1));
      v = fminf(v, __shfl_xor(v, 2));
      v = fminf(v, __shfl_xor(v, 4));
      v = fminf(v, __shfl_xor(v, 8));
      if (lr == 0) {
        int q = qbase + m_ * 16 + (lane >> 4) * 4 + r;
        atomicMin(&minbits[q], __float_as_uint(v));  // positive floats: uint order == float order
      }
    }
  }
}

// ---- patch scores + per-image max -------------------------------------
__global__ void scores_kernel(const uint32_t* __restrict__ minbits, const float* __restrict__ qn,
                              float* __restrict__ ps, float* __restrict__ img) {
  int q = blockIdx.x * 256 + threadIdx.x;
  if (q >= NQ) return;
  float s = __uint_as_float(minbits[q]) + qn[q];
  ps[q] = s;
  atomicMax((uint32_t*)&img[q / 784], __float_as_uint(s));  // scores > 0
}

// ---- bilinear 28x28 -> 224x224 (half-pixel centers, edge clamp) -------
__global__ void resize_kernel(const float* __restrict__ ps, float* __restrict__ masks) {
  int idx = blockIdx.x * 256 + threadIdx.x;
  if (idx >= NPIX) return;
  int b   = idx / (224 * 224);
  int rem = idx - b * (224 * 224);
  int oy  = rem / 224;
  int ox  = rem - oy * 224;
  float sy = (oy + 0.5f) * 0.125f - 0.5f;
  float sx = (ox + 0.5f) * 0.125f - 0.5f;
  float fy0 = floorf(sy), fx0 = floorf(sx);
  int y0 = (int)fy0, x0 = (int)fx0;
  float fy = sy - fy0, fx = sx - fx0;
  int y0c = min(max(y0, 0), 27),     y1c = min(max(y0 + 1, 0), 27);
  int x0c = min(max(x0, 0), 27),     x1c = min(max(x0 + 1, 0), 27);
  const float* p = ps + b * 784;
  float top = p[y0c * 28 + x0c] * (1.f - fx) + p[y0c * 28 + x1c] * fx;
  float bot = p[y1c * 28 + x0c] * (1.f - fx) + p[y1c * 28 + x1c] * fx;
  masks[idx] = top * (1.f - fy) + bot * fy;
}

// ---- host launch -------------------------------------------------------
extern "C" void kernel_launch(void* const* d_in, const int* in_sizes, int n_in,
                              void* d_out, int out_size, void* d_ws, size_t ws_size,
                              hipStream_t stream) {
  const float* features = (const float*)d_in[0];   // [6272, 1536]
  const float* bank     = (const float*)d_in[1];   // [50000, 1536]

  char* ws = (char*)d_ws;
  size_t off = 0;
  signed char* bankQ = (signed char*)(ws + off); off += (size_t)NBP2 * DIM;   // 77.1 MB
  signed char* featQ = (signed char*)(ws + off); off += (size_t)NQP * DIM;    //  9.8 MB
  float*    bn      = (float*)(ws + off);    off += (size_t)NBP2 * 4;
  float*    qn      = (float*)(ws + off);    off += (size_t)NQP * 4;
  float*    bscale  = (float*)(ws + off);    off += (size_t)NBP2 * 4;
  float*    qscale  = (float*)(ws + off);    off += (size_t)NQP * 4;
  uint32_t* minbits = (uint32_t*)(ws + off); off += (size_t)NQP * 4;
  float*    ps      = (float*)(ws + off);    off += (size_t)NQ * 4;

  float* out_scores = (float*)d_out;       // [8]
  float* masks      = out_scores + 8;      // [8,224,224]

  hipLaunchKernelGGL(init_kernel, dim3(25), dim3(256), 0, stream, minbits, out_scores);
  hipLaunchKernelGGL(quant_rows, dim3(NBP2 / 4), dim3(256), 0, stream, bank, bankQ, bn, bscale, NB, NBP2);
  hipLaunchKernelGGL(quant_rows, dim3(NQP / 4), dim3(256), 0, stream, features, featQ, qn, qscale, NQ, NQP);
  hipLaunchKernelGGL(gemm_min8, dim3(GRID3), dim3(512), 0, stream, featQ, bankQ, bn, bscale, qscale, minbits);
  hipLaunchKernelGGL(scores_kernel, dim3(25), dim3(256), 0, stream, minbits, qn, ps, out_scores);
  hipLaunchKernelGGL(resize_kernel, dim3((NPIX + 255) / 256), dim3(256), 0, stream, ps, masks);
}